// Round 7
// baseline (217.151 us; speedup 1.0000x reference)
//
#include <hip/hip_runtime.h>
#include <hip/hip_bf16.h>

// Problem constants
#define H_ 128
#define W_ 128
#define HW 16384          // H*W
#define CIN 64
#define COUT 128
#define KK9 9
#define BATCH 8
#define NPIX (BATCH * HW) // 131072
#define KDIM 576          // CIN*KK9

typedef short bf16x8 __attribute__((ext_vector_type(8)));
typedef float f32x4  __attribute__((ext_vector_type(4)));
typedef unsigned short ushort_t;

union U4B { uint4 u; bf16x8 v; };

__device__ __forceinline__ float us2f(unsigned short u) {
    unsigned int v = ((unsigned int)u) << 16;
    float f;
    __builtin_memcpy(&f, &v, 4);
    return f;
}
__device__ __forceinline__ float lo_f(unsigned int w) {
    unsigned int v = w << 16;
    float f;
    __builtin_memcpy(&f, &v, 4);
    return f;
}
__device__ __forceinline__ float hi_f(unsigned int w) {
    unsigned int v = w & 0xffff0000u;
    float f;
    __builtin_memcpy(&f, &v, 4);
    return f;
}
__device__ __forceinline__ unsigned short f2us_bf(float f) {
    __hip_bfloat16 h = __float2bfloat16(f);
    unsigned short u;
    __builtin_memcpy(&u, &h, 2);
    return u;
}
__device__ __forceinline__ unsigned int pack2(float a, float b) {
    return (unsigned int)f2us_bf(a) | ((unsigned int)f2us_bf(b) << 16);
}

template <bool F32>
__device__ __forceinline__ float ld_in(const void* p, long i) {
    if (F32) return ((const float*)p)[i];
    return us2f(((const unsigned short*)p)[i]);
}

// ---------------------------------------------------------------------------
// detect_zero: dtype probe (1 wave, vector loads, ballot) + zero gstat.
// ---------------------------------------------------------------------------
__global__ void detect_zero(const uint4* __restrict__ xr4,
                            float* __restrict__ flag,
                            float* __restrict__ gstat) {
    int t = threadIdx.x;   // 256
#pragma unroll
    for (int i = 0; i < 16; ++i) gstat[i * 256 + t] = 0.0f;
    if (t < 64) {
        uint4 v = xr4[t];
        unsigned int w[4] = {v.x, v.y, v.z, v.w};
        int big = 0;
#pragma unroll
        for (int q = 0; q < 4; ++q) {
            big += (((w[q] >> 7)  & 0xFF) >= 0xC0);
            big += (((w[q] >> 23) & 0xFF) >= 0xC0);
        }
        unsigned long long m = __ballot(big > 0);
        if (t == 0) flag[0] = m ? 1.0f : 0.0f;
    }
}

// ---------------------------------------------------------------------------
// prep_weights: weights in MFMA-fragment-linear order.
// ---------------------------------------------------------------------------
template <bool F32>
__device__ __forceinline__ void prep_body(const void* offw, const void* offb,
                                          const void* maskw, const void* maskb,
                                          const void* convw,
                                          ushort_t* wTs, ushort_t* wcats,
                                          float* bias, int i) {
    if (i < 73728) {
        int j = i & 7, lane = (i >> 3) & 63, n = (i >> 9) & 7, ks = i >> 12;
        int co = n * 16 + (lane & 15);
        int k  = ks * 32 + ((lane >> 4) << 3) + j;
        int kk = k >> 6, ci = k & 63;
        wTs[i] = f2us_bf(ld_in<F32>(convw, (long)co * KDIM + ci * 9 + kk));
    } else if (i < 73728 + 18432) {
        int i2 = i - 73728;
        int j = i2 & 7, lane = (i2 >> 3) & 63, n = (i2 >> 9) & 1, ks = i2 >> 10;
        int co2 = n * 16 + (lane & 15);
        int k   = ks * 32 + ((lane >> 4) << 3) + j;
        int kk = k >> 6, ci = k & 63;
        float v = 0.0f;
        if (co2 < 18)      v = ld_in<F32>(offw,  (long)co2 * KDIM + ci * 9 + kk);
        else if (co2 < 27) v = ld_in<F32>(maskw, (long)(co2 - 18) * KDIM + ci * 9 + kk);
        wcats[i2] = f2us_bf(v);
    } else if (i < 73728 + 18432 + 32) {
        int j = i - 73728 - 18432;
        float v = 0.0f;
        if (j < 18)      v = ld_in<F32>(offb, j);
        else if (j < 27) v = ld_in<F32>(maskb, j - 18);
        bias[j] = v;
    }
}

__global__ void prep_weights(const void* __restrict__ offw,
                             const void* __restrict__ offb,
                             const void* __restrict__ maskw,
                             const void* __restrict__ maskb,
                             const void* __restrict__ convw,
                             const float* __restrict__ flag,
                             ushort_t* __restrict__ wTs,
                             ushort_t* __restrict__ wcats,
                             float* __restrict__ bias) {
    int i = blockIdx.x * 256 + threadIdx.x;
    if (flag[0] != 0.0f)
        prep_body<true>(offw, offb, maskw, maskb, convw, wTs, wcats, bias, i);
    else
        prep_body<false>(offw, offb, maskw, maskb, convw, wTs, wcats, bias, i);
}

// ---------------------------------------------------------------------------
// transpose_x: raw x NCHW -> NHWC bf16. Vectorized (G13).
// ---------------------------------------------------------------------------
template <bool F32>
__device__ __forceinline__ void transpose_body(const void* x, ushort_t* xnb) {
    __shared__ float tile[CIN * 65];
    int blk  = blockIdx.x;
    int b    = blk >> 8;
    int pix0 = (blk & 255) * 64;
    int t    = threadIdx.x;
#pragma unroll
    for (int pass = 0; pass < 4; ++pass) {
        int slot = pass * 256 + t;
        int ci = slot >> 4;          // 0..63
        int f4 = slot & 15;          // 0..15 (4-px chunk)
        long base = (long)(b * CIN + ci) * HW + pix0 + f4 * 4;
        float v0, v1, v2, v3;
        if (F32) {
            float4 v = *(const float4*)((const float*)x + base);
            v0 = v.x; v1 = v.y; v2 = v.z; v3 = v.w;
        } else {
            ushort4 u = *(const ushort4*)((const ushort_t*)x + base);
            v0 = us2f(u.x); v1 = us2f(u.y); v2 = us2f(u.z); v3 = us2f(u.w);
        }
        tile[ci * 65 + f4 * 4 + 0] = v0;
        tile[ci * 65 + f4 * 4 + 1] = v1;
        tile[ci * 65 + f4 * 4 + 2] = v2;
        tile[ci * 65 + f4 * 4 + 3] = v3;
    }
    __syncthreads();
#pragma unroll
    for (int pass = 0; pass < 4; ++pass) {
        int slot = pass * 256 + t;
        int px = slot >> 4;          // 0..63
        int c4 = slot & 15;          // 0..15 (4-ch chunk)
        ushort4 o;
        o.x = f2us_bf(tile[(c4 * 4 + 0) * 65 + px]);
        o.y = f2us_bf(tile[(c4 * 4 + 1) * 65 + px]);
        o.z = f2us_bf(tile[(c4 * 4 + 2) * 65 + px]);
        o.w = f2us_bf(tile[(c4 * 4 + 3) * 65 + px]);
        *(ushort4*)(xnb + (size_t)(b * HW + pix0 + px) * CIN + c4 * 4) = o;
    }
}

__global__ __launch_bounds__(256) void transpose_x(const void* __restrict__ x,
                                                   const float* __restrict__ flag,
                                                   ushort_t* __restrict__ xnb) {
    if (flag[0] != 0.0f) transpose_body<true>(x, xnb);
    else                 transpose_body<false>(x, xnb);
}

// ---------------------------------------------------------------------------
// deform helpers (inner math IDENTICAL to R3-best; unchanged numerics).
// ---------------------------------------------------------------------------
__device__ __forceinline__ void compute_tap(int yp_t, int xp_t,
                                            float oy, float ox, float mk,
                                            int* ofs, float* wg) {
    float py  = (float)yp_t + oy;
    float pxf = (float)xp_t + ox;
    float y0f = floorf(py), x0f = floorf(pxf);
    int yi = (int)y0f, xi = (int)x0f;
    float wy1 = py - y0f, wx1 = pxf - x0f;
    float wy0 = 1.0f - wy1, wx0 = 1.0f - wx1;
    int ya  = min(max(yi, 0), H_ - 1);
    int yb  = min(max(yi + 1, 0), H_ - 1);
    int xa  = min(max(xi, 0), W_ - 1);
    int xb2 = min(max(xi + 1, 0), W_ - 1);
    bool vy0 = (yi >= 0) & (yi < H_);
    bool vy1 = (yi >= -1) & (yi < H_ - 1);
    bool vx0 = (xi >= 0) & (xi < W_);
    bool vx1 = (xi >= -1) & (xi < W_ - 1);
    float m0 = mk * wy0, m1 = mk * wy1;
    wg[0] = (vy0 & vx0) ? m0 * wx0 : 0.0f;
    wg[1] = (vy0 & vx1) ? m0 * wx1 : 0.0f;
    wg[2] = (vy1 & vx0) ? m1 * wx0 : 0.0f;
    wg[3] = (vy1 & vx1) ? m1 * wx1 : 0.0f;
    int ra = ya << 13, rb = yb << 13;   // y * W_ * CIN
    int ca = xa << 6,  cb_ = xb2 << 6;  // x * CIN
    ofs[0] = ra + ca;  ofs[1] = ra + cb_;
    ofs[2] = rb + ca;  ofs[3] = rb + cb_;
}

__device__ __forceinline__ void issue_half(const ushort_t* __restrict__ xb,
                                           const int* ofs, int hoff, uint4* cb) {
#pragma unroll
    for (int c = 0; c < 4; ++c)
        cb[c] = *(const uint4*)(xb + ofs[c] + hoff);
}

__device__ __forceinline__ void consume_half(int slot, const uint4* cb,
                                             const float* wg,
                                             const ushort_t* __restrict__ ldsB,
                                             int lane, f32x4* acc) {
    float2 v2[4];
#pragma unroll
    for (int j = 0; j < 4; ++j) v2[j] = make_float2(0.f, 0.f);
#pragma unroll
    for (int c = 0; c < 4; ++c) {
        float w = wg[c];
        unsigned int ww[4] = {cb[c].x, cb[c].y, cb[c].z, cb[c].w};
#pragma unroll
        for (int j = 0; j < 4; ++j) {
            v2[j].x = fmaf(w, lo_f(ww[j]), v2[j].x);
            v2[j].y = fmaf(w, hi_f(ww[j]), v2[j].y);
        }
    }
    U4B a;
    a.u = make_uint4(pack2(v2[0].x, v2[0].y), pack2(v2[1].x, v2[1].y),
                     pack2(v2[2].x, v2[2].y), pack2(v2[3].x, v2[3].y));
    const ushort_t* bbase = ldsB + ((size_t)(slot * 8) * 64 + lane) * 8;
    __builtin_amdgcn_s_setprio(1);
#pragma unroll
    for (int n = 0; n < 8; ++n) {
        bf16x8 bf = *(const bf16x8*)(bbase + n * 64 * 8);
        acc[n] = __builtin_amdgcn_mfma_f32_16x16x32_bf16(a.v, bf, acc[n], 0, 0, 0);
    }
    __builtin_amdgcn_s_setprio(0);
}

// ---------------------------------------------------------------------------
// fused_conv_deform: 1024 blocks x 512 thr (8 waves) / 128 px each.
// LDS = 62.5 KB -> TWO INDEPENDENT blocks co-resident per CU (16 waves/CU,
// same VGPR-capped wave count as before, but now in 2 blocks whose barriers
// and staging drains interleave: when block A stalls, block B's waves own
// the SIMDs). Conv phase: direct L2 gathers (R3-style reg preload, no
// x-tile, no bank conflicts), convB in LDS. Deform phase: B staged in 3
// stages of 6 K-slots (48 KB, restaged from L2-resident wTs); half-tap
// lookahead-2 ring; math identical to R3-best.
// ---------------------------------------------------------------------------
__global__ __launch_bounds__(512, 4) void fused_conv_deform(
        const ushort_t* __restrict__ xnb,
        const ushort_t* __restrict__ wcats,
        const float* __restrict__ bias,
        const ushort_t* __restrict__ wTs,
        ushort_t* __restrict__ prebn,
        float* __restrict__ gstat) {
    __shared__ uint4 lds[4000];              // 64,000 B total
    float2* offL  = (float2*)(lds + 3072);   // 9*128 float2 ( 9,216 B)
    float*  maskS = (float*) (lds + 3648);   // 9*128 f32    ( 4,608 B)
    float*  red   = (float*) (lds + 3936);   // 256 f32      ( 1,024 B)

    int t    = threadIdx.x;
    int bid  = blockIdx.x;
    int sbid = (bid & 7) * 128 + (bid >> 3);  // 1024 = 8 XCDs x 128, bijective
    int pix0 = sbid * 128;
    int b    = pix0 >> 14;
    int rem0 = pix0 & 16383;
    int y0   = rem0 >> 7;                     // single output row per block

    // stage convB (36,864 B) into lds[0..2304)
    const uint4* wc4 = (const uint4*)wcats;
    for (int i = t; i < 2304; i += 512) lds[i] = wc4[i];
    if (t < 256) red[t] = 0.0f;

    int wave = t >> 6, lane = t & 63, mrow = lane & 15, quad = lane >> 4;
    int px_l = wave * 16 + mrow;              // 0..127
    int xp   = px_l;                          // x coordinate (one row)
    const ushort_t* xb = xnb + (size_t)b * HW * CIN + quad * 8;

    // ---- conv phase: preload 9 taps direct from L2 (independent loads) ----
    uint4 af0[9], af1[9];
#pragma unroll
    for (int kk = 0; kk < 9; ++kk) {
        int yy = y0 + kk / 3 - 1;
        int xq = xp + kk % 3 - 1;
        bool ok = (yy >= 0) && (yy < H_) && (xq >= 0) && (xq < W_);
        const ushort_t* src = xb + (size_t)(yy * W_ + xq) * CIN;
        af0[kk] = ok ? *(const uint4*)src        : make_uint4(0, 0, 0, 0);
        af1[kk] = ok ? *(const uint4*)(src + 32) : make_uint4(0, 0, 0, 0);
    }
    __syncthreads();   // convB visible

    {
        f32x4 cacc[2];
        cacc[0] = (f32x4){0.f, 0.f, 0.f, 0.f};
        cacc[1] = (f32x4){0.f, 0.f, 0.f, 0.f};
        const ushort_t* ldsBc = (const ushort_t*)lds;
#pragma unroll
        for (int kk = 0; kk < 9; ++kk) {
#pragma unroll
            for (int half = 0; half < 2; ++half) {
                int ks = kk * 2 + half;
                U4B a; a.u = half ? af1[kk] : af0[kk];
#pragma unroll
                for (int n = 0; n < 2; ++n) {
                    bf16x8 bf = *(const bf16x8*)(ldsBc + ((ks * 2 + n) * 64 + lane) * 8);
                    cacc[n] = __builtin_amdgcn_mfma_f32_16x16x32_bf16(a.v, bf, cacc[n], 0, 0, 0);
                }
            }
        }
#pragma unroll
        for (int n = 0; n < 2; ++n) {
            int co2 = n * 16 + mrow;
            if (co2 >= 27) continue;
            float bs = bias[co2];
#pragma unroll
            for (int r = 0; r < 4; ++r) {
                int px = wave * 16 + quad * 4 + r;
                float v = cacc[n][r] + bs;
                if (co2 < 18)
                    ((float*)offL)[((co2 >> 1) * 128 + px) * 2 + (co2 & 1)] = v;
                else
                    maskS[(co2 - 18) * 128 + px] = 1.0f / (1.0f + __expf(-v));
            }
        }
    }
    __syncthreads();   // convB reads done; offL/maskS visible

    // ---- deform phase: B stage 0 + gather-ring prologue ----
    const uint4* ws4 = (const uint4*)wTs;
    for (int i = t; i < 3072; i += 512) lds[i] = ws4[i];

    int remp = rem0 + px_l;
    int yp  = remp >> 7, xp2 = remp & 127;

    f32x4 acc[8];
#pragma unroll
    for (int n = 0; n < 8; ++n) acc[n] = (f32x4){0.f, 0.f, 0.f, 0.f};

    int   ofs[2][4];
    float wg[2][4];
    uint4 cb[3][4];

    float2 oE  = offL[px_l];           float mkE = maskS[px_l];
    float2 oO  = offL[128 + px_l];     float mkO = maskS[128 + px_l];
    compute_tap(yp - 1, xp2 - 1, oE.x, oE.y, mkE, ofs[0], wg[0]);
    issue_half(xb, ofs[0], 0,  cb[0]);
    issue_half(xb, ofs[0], 32, cb[1]);
    oE = offL[2 * 128 + px_l];  mkE = maskS[2 * 128 + px_l];
    __builtin_amdgcn_sched_barrier(0);
    __syncthreads();   // B stage 0 visible

    const ushort_t* ldsB = (const ushort_t*)lds;

#define ISSUE_STEP(hs)  do {                                                  \
    const int hs2 = (hs) + 2;                                                 \
    if (hs2 < 18) {                                                           \
        const int kk2 = hs2 >> 1;                                             \
        const int s2  = hs2 % 3;                                              \
        if ((hs2 & 1) == 0) {                                                 \
            const int tp2 = kk2 & 1;                                          \
            float ooy = tp2 ? oO.x : oE.x;                                    \
            float oox = tp2 ? oO.y : oE.y;                                    \
            float omk = tp2 ? mkO  : mkE;                                     \
            compute_tap(yp + kk2 / 3 - 1, xp2 + kk2 % 3 - 1, ooy, oox, omk,   \
                        ofs[tp2], wg[tp2]);                                   \
            issue_half(xb, ofs[tp2], 0, cb[s2]);                              \
            if (kk2 + 2 <= 8) {                                               \
                float2 o = offL[(kk2 + 2) * 128 + px_l];                      \
                float  m = maskS[(kk2 + 2) * 128 + px_l];                     \
                if (tp2) { oO = o; mkO = m; } else { oE = o; mkE = m; }       \
            }                                                                 \
        } else {                                                              \
            issue_half(xb, ofs[kk2 & 1], 32, cb[s2]);                         \
        }                                                                     \
    }                                                                         \
    __builtin_amdgcn_sched_barrier(0);                                        \
} while (0)

    // stage 0: hs 0..5 (slots 0..5)
#pragma unroll
    for (int hs = 0; hs < 6; ++hs) {
        ISSUE_STEP(hs);
        consume_half(hs, cb[hs % 3], wg[(hs >> 1) & 1], ldsB, lane, acc);
    }
    __syncthreads();
    for (int i = t; i < 3072; i += 512) lds[i] = ws4[3072 + i];
    __syncthreads();
    // stage 1: hs 6..11 (slots 0..5)
#pragma unroll
    for (int hs = 6; hs < 12; ++hs) {
        ISSUE_STEP(hs);
        consume_half(hs - 6, cb[hs % 3], wg[(hs >> 1) & 1], ldsB, lane, acc);
    }
    __syncthreads();
    for (int i = t; i < 3072; i += 512) lds[i] = ws4[6144 + i];
    __syncthreads();
    // stage 2: hs 12..17 (slots 0..5)
#pragma unroll
    for (int hs = 12; hs < 18; ++hs) {
        ISSUE_STEP(hs);
        consume_half(hs - 12, cb[hs % 3], wg[(hs >> 1) & 1], ldsB, lane, acc);
    }
#undef ISSUE_STEP

    // ---- epilogue: bf16 NHWC store + BN stats (shuffle-reduce) ----
#pragma unroll
    for (int n = 0; n < 8; ++n) {
        int co = n * 16 + mrow;
        float s = 0.f, ss = 0.f;
#pragma unroll
        for (int r = 0; r < 4; ++r) {
            int pg = pix0 + wave * 16 + quad * 4 + r;
            float v = acc[n][r];
            prebn[(size_t)pg * COUT + co] = f2us_bf(v);
            s += v;
            ss += v * v;
        }
        s  += __shfl_xor(s, 16, 64);
        s  += __shfl_xor(s, 32, 64);
        ss += __shfl_xor(ss, 16, 64);
        ss += __shfl_xor(ss, 32, 64);
        if (quad == 0) {
            atomicAdd(&red[co], s);
            atomicAdd(&red[128 + co], ss);
        }
    }
    __syncthreads();
    if (t < 256) atomicAdd(&gstat[(bid & 15) * 256 + t], red[t]);
}

// ---------------------------------------------------------------------------
// bn_apply_t: derive mean/rstd from gstat; vectorized uint4 reads + float4
// writes via padded LDS transpose tile.
// ---------------------------------------------------------------------------
__global__ __launch_bounds__(256) void bn_apply_t(const ushort_t* __restrict__ prebn,
                                                  const float* __restrict__ gstat,
                                                  float* __restrict__ out) {
    __shared__ float tile[128 * 65];
    __shared__ float mvs[256];
    int t = threadIdx.x;
    if (t < 128) {
        float s = 0.f, ss = 0.f;
#pragma unroll
        for (int part = 0; part < 16; ++part) {
            s  += gstat[part * 256 + t];
            ss += gstat[part * 256 + 128 + t];
        }
        const float invN = 1.0f / (float)NPIX;
        float mean = s * invN;
        float var  = ss * invN - mean * mean;
        if (!isfinite(mean)) mean = 0.0f;
        float r = rsqrtf(fmaxf(var, 0.0f) + 1e-5f);
        if (!isfinite(r)) r = 1.0f;
        mvs[t]       = mean;
        mvs[128 + t] = r;
    }
    __syncthreads();
    int pix0 = blockIdx.x * 64;
    int b    = pix0 >> 14;
    int rem0 = pix0 & 16383;
    const uint4* src4 = (const uint4*)(prebn + (size_t)pix0 * COUT);
#pragma unroll
    for (int r = 0; r < 4; ++r) {
        int i  = r * 256 + t;        // uint4 index 0..1023
        uint4 v = src4[i];
        int p  = i >> 4;             // pixel 0..63
        int c0 = (i & 15) * 8;       // channel base
        unsigned int w[4] = {v.x, v.y, v.z, v.w};
#pragma unroll
        for (int j = 0; j < 4; ++j) {
            int c = c0 + j * 2;
            float f0 = lo_f(w[j]);
            float f1 = hi_f(w[j]);
            tile[c * 65 + p]       = fmaxf((f0 - mvs[c])     * mvs[128 + c],     0.0f);
            tile[(c + 1) * 65 + p] = fmaxf((f1 - mvs[c + 1]) * mvs[128 + c + 1], 0.0f);
        }
    }
    __syncthreads();
#pragma unroll
    for (int r = 0; r < 8; ++r) {
        int i  = r * 256 + t;        // float4 index 0..2047
        int c2 = i >> 4;             // 0..127
        int q  = (i & 15) * 4;       // 0..60
        float4 w4 = make_float4(tile[c2 * 65 + q],     tile[c2 * 65 + q + 1],
                                tile[c2 * 65 + q + 2], tile[c2 * 65 + q + 3]);
        *(float4*)(out + (size_t)(b * COUT + c2) * HW + rem0 + q) = w4;
    }
}

// ---------------------------------------------------------------------------
extern "C" void kernel_launch(void* const* d_in, const int* in_sizes, int n_in,
                              void* d_out, int out_size, void* d_ws, size_t ws_size,
                              hipStream_t stream) {
    (void)in_sizes; (void)n_in; (void)out_size; (void)ws_size;
    const void* x     = d_in[0];
    const void* offw  = d_in[1];
    const void* offb  = d_in[2];
    const void* maskw = d_in[3];
    const void* maskb = d_in[4];
    const void* convw = d_in[5];

    float* ws       = (float*)d_ws;
    float* off2     = ws;                      // (unused after fusion)
    float* mask_ws  = off2 + 2359296;          // (unused after fusion)
    float* bias     = mask_ws + 1179648;       //        32 f32
    float* gstat    = bias + 32;               //     4,096 f32
    float* flag     = gstat + 4096;            //        16 f32
    ushort_t* wTs   = (ushort_t*)(flag + 16);  //    73,728 bf16 (frag-linear)
    ushort_t* wcats = wTs + 73728;             //    18,432 bf16 (frag-linear)
    ushort_t* xnb   = wcats + 18432;           // 8,388,608 bf16 (NHWC x)
    ushort_t* prebn = xnb + 8388608;           // 16,777,216 bf16 (NHWC pre-BN)
    float* out      = (float*)d_out;

    detect_zero<<<1, 256, 0, stream>>>((const uint4*)x, flag, gstat);
    prep_weights<<<361, 256, 0, stream>>>(offw, offb, maskw, maskb, convw, flag, wTs, wcats, bias);
    transpose_x<<<2048, 256, 0, stream>>>(x, flag, xnb);
    fused_conv_deform<<<1024, 512, 0, stream>>>(xnb, wcats, bias, wTs, prebn, gstat);
    bn_apply_t<<<2048, 256, 0, stream>>>(prebn, gstat, out);
}

// Round 8
// 198.664 us; speedup vs baseline: 1.0931x; 1.0931x over previous
//
#include <hip/hip_runtime.h>
#include <hip/hip_bf16.h>

// Problem constants
#define H_ 128
#define W_ 128
#define HW 16384          // H*W
#define CIN 64
#define COUT 128
#define KK9 9
#define BATCH 8
#define NPIX (BATCH * HW) // 131072
#define KDIM 576          // CIN*KK9

typedef short bf16x8 __attribute__((ext_vector_type(8)));
typedef float f32x4  __attribute__((ext_vector_type(4)));
typedef unsigned short ushort_t;

union U4B { uint4 u; bf16x8 v; };

__device__ __forceinline__ float us2f(unsigned short u) {
    unsigned int v = ((unsigned int)u) << 16;
    float f;
    __builtin_memcpy(&f, &v, 4);
    return f;
}
__device__ __forceinline__ float lo_f(unsigned int w) {
    unsigned int v = w << 16;
    float f;
    __builtin_memcpy(&f, &v, 4);
    return f;
}
__device__ __forceinline__ float hi_f(unsigned int w) {
    unsigned int v = w & 0xffff0000u;
    float f;
    __builtin_memcpy(&f, &v, 4);
    return f;
}
__device__ __forceinline__ unsigned short f2us_bf(float f) {
    __hip_bfloat16 h = __float2bfloat16(f);
    unsigned short u;
    __builtin_memcpy(&u, &h, 2);
    return u;
}
__device__ __forceinline__ unsigned int pack2(float a, float b) {
    return (unsigned int)f2us_bf(a) | ((unsigned int)f2us_bf(b) << 16);
}

template <bool F32>
__device__ __forceinline__ float ld_in(const void* p, long i) {
    if (F32) return ((const float*)p)[i];
    return us2f(((const unsigned short*)p)[i]);
}

// ---------------------------------------------------------------------------
// prep bodies (unchanged math).
// ---------------------------------------------------------------------------
template <bool F32>
__device__ __forceinline__ void prep_body(const void* offw, const void* offb,
                                          const void* maskw, const void* maskb,
                                          const void* convw,
                                          ushort_t* wTs, ushort_t* wcats,
                                          float* bias, int i) {
    if (i < 73728) {
        int j = i & 7, lane = (i >> 3) & 63, n = (i >> 9) & 7, ks = i >> 12;
        int co = n * 16 + (lane & 15);
        int k  = ks * 32 + ((lane >> 4) << 3) + j;
        int kk = k >> 6, ci = k & 63;
        wTs[i] = f2us_bf(ld_in<F32>(convw, (long)co * KDIM + ci * 9 + kk));
    } else if (i < 73728 + 18432) {
        int i2 = i - 73728;
        int j = i2 & 7, lane = (i2 >> 3) & 63, n = (i2 >> 9) & 1, ks = i2 >> 10;
        int co2 = n * 16 + (lane & 15);
        int k   = ks * 32 + ((lane >> 4) << 3) + j;
        int kk = k >> 6, ci = k & 63;
        float v = 0.0f;
        if (co2 < 18)      v = ld_in<F32>(offw,  (long)co2 * KDIM + ci * 9 + kk);
        else if (co2 < 27) v = ld_in<F32>(maskw, (long)(co2 - 18) * KDIM + ci * 9 + kk);
        wcats[i2] = f2us_bf(v);
    } else if (i < 73728 + 18432 + 32) {
        int j = i - 73728 - 18432;
        float v = 0.0f;
        if (j < 18)      v = ld_in<F32>(offb, j);
        else if (j < 27) v = ld_in<F32>(maskb, j - 18);
        bias[j] = v;
    }
}

template <bool F32>
__device__ __forceinline__ void transpose_body(const void* x, ushort_t* xnb,
                                               int blk) {
    __shared__ float tile[CIN * 65];
    int b    = blk >> 8;
    int pix0 = (blk & 255) * 64;
    int t    = threadIdx.x;
#pragma unroll
    for (int pass = 0; pass < 4; ++pass) {
        int slot = pass * 256 + t;
        int ci = slot >> 4;          // 0..63
        int f4 = slot & 15;          // 0..15 (4-px chunk)
        long base = (long)(b * CIN + ci) * HW + pix0 + f4 * 4;
        float v0, v1, v2, v3;
        if (F32) {
            float4 v = *(const float4*)((const float*)x + base);
            v0 = v.x; v1 = v.y; v2 = v.z; v3 = v.w;
        } else {
            ushort4 u = *(const ushort4*)((const ushort_t*)x + base);
            v0 = us2f(u.x); v1 = us2f(u.y); v2 = us2f(u.z); v3 = us2f(u.w);
        }
        tile[ci * 65 + f4 * 4 + 0] = v0;
        tile[ci * 65 + f4 * 4 + 1] = v1;
        tile[ci * 65 + f4 * 4 + 2] = v2;
        tile[ci * 65 + f4 * 4 + 3] = v3;
    }
    __syncthreads();
#pragma unroll
    for (int pass = 0; pass < 4; ++pass) {
        int slot = pass * 256 + t;
        int px = slot >> 4;          // 0..63
        int c4 = slot & 15;          // 0..15 (4-ch chunk)
        ushort4 o;
        o.x = f2us_bf(tile[(c4 * 4 + 0) * 65 + px]);
        o.y = f2us_bf(tile[(c4 * 4 + 1) * 65 + px]);
        o.z = f2us_bf(tile[(c4 * 4 + 2) * 65 + px]);
        o.w = f2us_bf(tile[(c4 * 4 + 3) * 65 + px]);
        *(ushort4*)(xnb + (size_t)(b * HW + pix0 + px) * CIN + c4 * 4) = o;
    }
}

// ---------------------------------------------------------------------------
// prep_mega: ONE kernel = dtype-probe (per-block, 1KB L2-broadcast read of x)
// + prep_weights (blocks 0..360) + transpose_x (blocks 361..2408) + gstat
// zeroing (blocks 0..15). Removes the detect_zero launch and the flag
// round-trip: 5 launches -> 3 (launch-gap overhead was ~1/3 of total).
// ---------------------------------------------------------------------------
__global__ __launch_bounds__(256) void prep_mega(
        const void* __restrict__ x,
        const void* __restrict__ offw,
        const void* __restrict__ offb,
        const void* __restrict__ maskw,
        const void* __restrict__ maskb,
        const void* __restrict__ convw,
        ushort_t* __restrict__ wTs,
        ushort_t* __restrict__ wcats,
        float* __restrict__ bias,
        float* __restrict__ gstat,
        ushort_t* __restrict__ xnb) {
    __shared__ float flagS;
    int t   = threadIdx.x;
    int blk = blockIdx.x;

    // per-block dtype probe (same 1KB of x for every block -> L2 broadcast)
    if (t < 64) {
        uint4 v = ((const uint4*)x)[t];
        unsigned int w[4] = {v.x, v.y, v.z, v.w};
        int big = 0;
#pragma unroll
        for (int q = 0; q < 4; ++q) {
            big += (((w[q] >> 7)  & 0xFF) >= 0xC0);
            big += (((w[q] >> 23) & 0xFF) >= 0xC0);
        }
        unsigned long long m = __ballot(big > 0);
        if (t == 0) flagS = m ? 1.0f : 0.0f;
    }
    if (blk < 16) gstat[blk * 256 + t] = 0.0f;
    __syncthreads();
    bool isF32 = (flagS != 0.0f);

    if (blk < 361) {
        int i = blk * 256 + t;
        if (isF32) prep_body<true >(offw, offb, maskw, maskb, convw, wTs, wcats, bias, i);
        else       prep_body<false>(offw, offb, maskw, maskb, convw, wTs, wcats, bias, i);
    } else {
        int tb = blk - 361;
        if (isF32) transpose_body<true >(x, xnb, tb);
        else       transpose_body<false>(x, xnb, tb);
    }
}

// ---------------------------------------------------------------------------
// deform helpers (R6 version, unchanged numerics).
// ---------------------------------------------------------------------------
__device__ __forceinline__ void compute_tap(int yp_t, int xp_t,
                                            float oy, float ox, float mk,
                                            int* ofs, float* wg) {
    float py  = (float)yp_t + oy;
    float pxf = (float)xp_t + ox;
    float y0f = floorf(py), x0f = floorf(pxf);
    int yi = (int)y0f, xi = (int)x0f;
    float wy1 = py - y0f, wx1 = pxf - x0f;
    float wy0 = 1.0f - wy1, wx0 = 1.0f - wx1;
    int ya  = min(max(yi, 0), H_ - 1);
    int yb  = min(max(yi + 1, 0), H_ - 1);
    int xa  = min(max(xi, 0), W_ - 1);
    int xb2 = min(max(xi + 1, 0), W_ - 1);
    bool vy0 = (yi >= 0) & (yi < H_);
    bool vy1 = (yi >= -1) & (yi < H_ - 1);
    bool vx0 = (xi >= 0) & (xi < W_);
    bool vx1 = (xi >= -1) & (xi < W_ - 1);
    float m0 = mk * wy0, m1 = mk * wy1;
    wg[0] = (vy0 & vx0) ? m0 * wx0 : 0.0f;
    wg[1] = (vy0 & vx1) ? m0 * wx1 : 0.0f;
    wg[2] = (vy1 & vx0) ? m1 * wx0 : 0.0f;
    wg[3] = (vy1 & vx1) ? m1 * wx1 : 0.0f;
    int ra = ya << 13, rb = yb << 13;   // y * W_ * CIN
    int ca = xa << 6,  cb_ = xb2 << 6;  // x * CIN
    ofs[0] = ra + ca;  ofs[1] = ra + cb_;
    ofs[2] = rb + ca;  ofs[3] = rb + cb_;
}

__device__ __forceinline__ void issue_half(const ushort_t* __restrict__ xb,
                                           const int* ofs, int hoff, uint4* cb) {
#pragma unroll
    for (int c = 0; c < 4; ++c)
        cb[c] = *(const uint4*)(xb + ofs[c] + hoff);
}

__device__ __forceinline__ void consume_half(int slot, const uint4* cb,
                                             const float* wg,
                                             const ushort_t* __restrict__ ldsB,
                                             int lane, f32x4* acc) {
    float2 v2[4];
#pragma unroll
    for (int j = 0; j < 4; ++j) v2[j] = make_float2(0.f, 0.f);
#pragma unroll
    for (int c = 0; c < 4; ++c) {
        float w = wg[c];
        unsigned int ww[4] = {cb[c].x, cb[c].y, cb[c].z, cb[c].w};
#pragma unroll
        for (int j = 0; j < 4; ++j) {
            v2[j].x = fmaf(w, lo_f(ww[j]), v2[j].x);
            v2[j].y = fmaf(w, hi_f(ww[j]), v2[j].y);
        }
    }
    U4B a;
    a.u = make_uint4(pack2(v2[0].x, v2[0].y), pack2(v2[1].x, v2[1].y),
                     pack2(v2[2].x, v2[2].y), pack2(v2[3].x, v2[3].y));
    const ushort_t* bbase = ldsB + ((size_t)(slot * 8) * 64 + lane) * 8;
    __builtin_amdgcn_s_setprio(1);
#pragma unroll
    for (int n = 0; n < 8; ++n) {
        bf16x8 bf = *(const bf16x8*)(bbase + n * 64 * 8);
        acc[n] = __builtin_amdgcn_mfma_f32_16x16x32_bf16(a.v, bf, acc[n], 0, 0, 0);
    }
    __builtin_amdgcn_s_setprio(0);
}

// ---------------------------------------------------------------------------
// fused_conv_deform: EXACT R6 version (measured 98.8us). conv phase (x-tile
// in LDS, swizzled) + deform phase (B K-split 2x, half-tap LA-2 ring).
// ---------------------------------------------------------------------------
__global__ __launch_bounds__(1024, 4) void fused_conv_deform(
        const ushort_t* __restrict__ xnb,
        const ushort_t* __restrict__ wcats,
        const float* __restrict__ bias,
        const ushort_t* __restrict__ wTs,
        ushort_t* __restrict__ prebn,
        float* __restrict__ gstat) {
    __shared__ uint4 lds[8192];   // 131,072 B

    float2* offL  = (float2*)(lds + 6400);   // 9*256 float2 (18,432 B)
    float*  maskS = (float*) (lds + 7552);   // 9*256 f32    ( 9,216 B)
    float*  red   = (float*) (lds + 8128);   // 256 f32      ( 1,024 B)

    int t    = threadIdx.x;
    int bid  = blockIdx.x;
    int sbid = (bid & 7) * 64 + (bid >> 3);   // 512 = 8 XCDs x 64, bijective
    int pix0 = sbid * 256;
    int b    = pix0 >> 14;
    int rem0 = pix0 & 16383;
    int y0   = rem0 >> 7;

    // ---- phase 0: stage convB + 4-row x-tile (swizzled) ----
    const uint4* wc4 = (const uint4*)wcats;
    for (int i = t; i < 2304; i += 1024) lds[i] = wc4[i];
    const uint4* xrow4 = (const uint4*)(xnb + (size_t)b * HW * CIN);
    int sxq = t >> 3, sc16 = t & 7;
#pragma unroll
    for (int r = 0; r < 4; ++r) {
        int gy = y0 - 1 + r;
        if (gy >= 0 && gy < H_) {
            uint4 v = xrow4[(size_t)gy * 1024 + t];
            lds[2304 + r * 1024 + sxq * 8 + (sc16 ^ (sxq & 7))] = v;
        }
    }
    if (t < 256) red[t] = 0.0f;
    __syncthreads();

    int wave = t >> 6, lane = t & 63, mrow = lane & 15, quad = lane >> 4;
    int px_l = wave * 16 + mrow;

    // ---- phase 1: conv 27-ch -> offL/maskS in LDS ----
    {
        int ly = px_l >> 7;
        int xp = px_l & 127;
        uint4 af0[9], af1[9];
#pragma unroll
        for (int kk = 0; kk < 9; ++kk) {
            int ty = kk / 3, tx = kk % 3;
            int tr = ly + ty;
            int gy = y0 - 1 + tr;
            int xq = xp + tx - 1;
            bool ok = (gy >= 0) && (gy < H_) && (xq >= 0) && (xq < W_);
            int xc = min(max(xq, 0), W_ - 1);
            int base = 2304 + tr * 1024 + xc * 8;
            uint4 a0 = lds[base + ((quad    ) ^ (xc & 7))];
            uint4 a1 = lds[base + ((quad + 4) ^ (xc & 7))];
            af0[kk] = ok ? a0 : make_uint4(0, 0, 0, 0);
            af1[kk] = ok ? a1 : make_uint4(0, 0, 0, 0);
        }
        f32x4 cacc[2];
        cacc[0] = (f32x4){0.f, 0.f, 0.f, 0.f};
        cacc[1] = (f32x4){0.f, 0.f, 0.f, 0.f};
        const ushort_t* ldsBc = (const ushort_t*)lds;
#pragma unroll
        for (int kk = 0; kk < 9; ++kk) {
#pragma unroll
            for (int half = 0; half < 2; ++half) {
                int ks = kk * 2 + half;
                U4B a; a.u = half ? af1[kk] : af0[kk];
#pragma unroll
                for (int n = 0; n < 2; ++n) {
                    bf16x8 bf = *(const bf16x8*)(ldsBc + ((ks * 2 + n) * 64 + lane) * 8);
                    cacc[n] = __builtin_amdgcn_mfma_f32_16x16x32_bf16(a.v, bf, cacc[n], 0, 0, 0);
                }
            }
        }
#pragma unroll
        for (int n = 0; n < 2; ++n) {
            int co2 = n * 16 + mrow;
            if (co2 >= 27) continue;
            float bs = bias[co2];
#pragma unroll
            for (int r = 0; r < 4; ++r) {
                int px = wave * 16 + quad * 4 + r;
                float v = cacc[n][r] + bs;
                if (co2 < 18)
                    ((float*)offL)[((co2 >> 1) * 256 + px) * 2 + (co2 & 1)] = v;
                else
                    maskS[(co2 - 18) * 256 + px] = 1.0f / (1.0f + __expf(-v));
            }
        }
    }
    __syncthreads();   // x-tile/convB reads done; offL/maskS visible

    // ---- phase 2: stage deform B half0 + gather-ring prologue ----
    const uint4* ws4 = (const uint4*)wTs;
    for (int i = t; i < 4608; i += 1024) lds[i] = ws4[i];

    int remp = rem0 + px_l;
    int yp  = remp >> 7, xp2 = remp & 127;
    const ushort_t* xb = xnb + (size_t)b * HW * CIN + quad * 8;

    f32x4 acc[8];
#pragma unroll
    for (int n = 0; n < 8; ++n) acc[n] = (f32x4){0.f, 0.f, 0.f, 0.f};

    int   ofs[2][4];
    float wg[2][4];
    uint4 cb[3][4];

    float2 oE  = offL[px_l];           float mkE = maskS[px_l];
    float2 oO  = offL[256 + px_l];     float mkO = maskS[256 + px_l];
    compute_tap(yp - 1, xp2 - 1, oE.x, oE.y, mkE, ofs[0], wg[0]);
    issue_half(xb, ofs[0], 0,  cb[0]);
    issue_half(xb, ofs[0], 32, cb[1]);
    oE = offL[2 * 256 + px_l];  mkE = maskS[2 * 256 + px_l];
    __builtin_amdgcn_sched_barrier(0);
    __syncthreads();   // B half0 visible

    const ushort_t* ldsB = (const ushort_t*)lds;

#pragma unroll
    for (int hs = 0; hs < 9; ++hs) {
        const int hs2 = hs + 2;                // 2..10, always valid
        {
            const int kk2 = hs2 >> 1;
            const int s2  = hs2 % 3;
            if ((hs2 & 1) == 0) {
                const int tp2 = kk2 & 1;
                float ooy = tp2 ? oO.x : oE.x;
                float oox = tp2 ? oO.y : oE.y;
                float omk = tp2 ? mkO  : mkE;
                compute_tap(yp + kk2 / 3 - 1, xp2 + kk2 % 3 - 1, ooy, oox, omk,
                            ofs[tp2], wg[tp2]);
                issue_half(xb, ofs[tp2], 0, cb[s2]);
                if (kk2 + 2 <= 8) {
                    float2 o = offL[(kk2 + 2) * 256 + px_l];
                    float  m = maskS[(kk2 + 2) * 256 + px_l];
                    if (tp2) { oO = o; mkO = m; } else { oE = o; mkE = m; }
                }
            } else {
                issue_half(xb, ofs[kk2 & 1], 32, cb[s2]);
            }
        }
        __builtin_amdgcn_sched_barrier(0);
        consume_half(hs, cb[hs % 3], wg[(hs >> 1) & 1], ldsB, lane, acc);
    }
    __syncthreads();   // half0 reads done
    for (int i = t; i < 4608; i += 1024) lds[i] = ws4[4608 + i];
    __syncthreads();   // half1 visible

#pragma unroll
    for (int hs = 9; hs < 18; ++hs) {
        const int hs2 = hs + 2;
        if (hs2 < 18) {
            const int kk2 = hs2 >> 1;
            const int s2  = hs2 % 3;
            if ((hs2 & 1) == 0) {
                const int tp2 = kk2 & 1;
                float ooy = tp2 ? oO.x : oE.x;
                float oox = tp2 ? oO.y : oE.y;
                float omk = tp2 ? mkO  : mkE;
                compute_tap(yp + kk2 / 3 - 1, xp2 + kk2 % 3 - 1, ooy, oox, omk,
                            ofs[tp2], wg[tp2]);
                issue_half(xb, ofs[tp2], 0, cb[s2]);
                if (kk2 + 2 <= 8) {
                    float2 o = offL[(kk2 + 2) * 256 + px_l];
                    float  m = maskS[(kk2 + 2) * 256 + px_l];
                    if (tp2) { oO = o; mkO = m; } else { oE = o; mkE = m; }
                }
            } else {
                issue_half(xb, ofs[kk2 & 1], 32, cb[s2]);
            }
        }
        __builtin_amdgcn_sched_barrier(0);
        consume_half(hs - 9, cb[hs % 3], wg[(hs >> 1) & 1], ldsB, lane, acc);
    }

    // ---- epilogue: bf16 NHWC store + BN stats (shuffle-reduce) ----
#pragma unroll
    for (int n = 0; n < 8; ++n) {
        int co = n * 16 + mrow;
        float s = 0.f, ss = 0.f;
#pragma unroll
        for (int r = 0; r < 4; ++r) {
            int pg = pix0 + wave * 16 + quad * 4 + r;
            float v = acc[n][r];
            prebn[(size_t)pg * COUT + co] = f2us_bf(v);
            s += v;
            ss += v * v;
        }
        s  += __shfl_xor(s, 16, 64);
        s  += __shfl_xor(s, 32, 64);
        ss += __shfl_xor(ss, 16, 64);
        ss += __shfl_xor(ss, 32, 64);
        if (quad == 0) {
            atomicAdd(&red[co], s);
            atomicAdd(&red[128 + co], ss);
        }
    }
    __syncthreads();
    if (t < 256) atomicAdd(&gstat[(bid & 15) * 256 + t], red[t]);
}

// ---------------------------------------------------------------------------
// bn_apply_t: derive mean/rstd from gstat; vectorized uint4 reads + float4
// writes via padded LDS transpose tile.
// ---------------------------------------------------------------------------
__global__ __launch_bounds__(256) void bn_apply_t(const ushort_t* __restrict__ prebn,
                                                  const float* __restrict__ gstat,
                                                  float* __restrict__ out) {
    __shared__ float tile[128 * 65];
    __shared__ float mvs[256];
    int t = threadIdx.x;
    if (t < 128) {
        float s = 0.f, ss = 0.f;
#pragma unroll
        for (int part = 0; part < 16; ++part) {
            s  += gstat[part * 256 + t];
            ss += gstat[part * 256 + 128 + t];
        }
        const float invN = 1.0f / (float)NPIX;
        float mean = s * invN;
        float var  = ss * invN - mean * mean;
        if (!isfinite(mean)) mean = 0.0f;
        float r = rsqrtf(fmaxf(var, 0.0f) + 1e-5f);
        if (!isfinite(r)) r = 1.0f;
        mvs[t]       = mean;
        mvs[128 + t] = r;
    }
    __syncthreads();
    int pix0 = blockIdx.x * 64;
    int b    = pix0 >> 14;
    int rem0 = pix0 & 16383;
    const uint4* src4 = (const uint4*)(prebn + (size_t)pix0 * COUT);
#pragma unroll
    for (int r = 0; r < 4; ++r) {
        int i  = r * 256 + t;        // uint4 index 0..1023
        uint4 v = src4[i];
        int p  = i >> 4;             // pixel 0..63
        int c0 = (i & 15) * 8;       // channel base
        unsigned int w[4] = {v.x, v.y, v.z, v.w};
#pragma unroll
        for (int j = 0; j < 4; ++j) {
            int c = c0 + j * 2;
            float f0 = lo_f(w[j]);
            float f1 = hi_f(w[j]);
            tile[c * 65 + p]       = fmaxf((f0 - mvs[c])     * mvs[128 + c],     0.0f);
            tile[(c + 1) * 65 + p] = fmaxf((f1 - mvs[c + 1]) * mvs[128 + c + 1], 0.0f);
        }
    }
    __syncthreads();
#pragma unroll
    for (int r = 0; r < 8; ++r) {
        int i  = r * 256 + t;        // float4 index 0..2047
        int c2 = i >> 4;             // 0..127
        int q  = (i & 15) * 4;       // 0..60
        float4 w4 = make_float4(tile[c2 * 65 + q],     tile[c2 * 65 + q + 1],
                                tile[c2 * 65 + q + 2], tile[c2 * 65 + q + 3]);
        *(float4*)(out + (size_t)(b * COUT + c2) * HW + rem0 + q) = w4;
    }
}

// ---------------------------------------------------------------------------
extern "C" void kernel_launch(void* const* d_in, const int* in_sizes, int n_in,
                              void* d_out, int out_size, void* d_ws, size_t ws_size,
                              hipStream_t stream) {
    (void)in_sizes; (void)n_in; (void)out_size; (void)ws_size;
    const void* x     = d_in[0];
    const void* offw  = d_in[1];
    const void* offb  = d_in[2];
    const void* maskw = d_in[3];
    const void* maskb = d_in[4];
    const void* convw = d_in[5];

    float* ws       = (float*)d_ws;
    float* off2     = ws;                      // (unused after fusion)
    float* mask_ws  = off2 + 2359296;          // (unused after fusion)
    float* bias     = mask_ws + 1179648;       //        32 f32
    float* gstat    = bias + 32;               //     4,096 f32
    float* flag     = gstat + 4096;            //        16 f32 (unused now)
    ushort_t* wTs   = (ushort_t*)(flag + 16);  //    73,728 bf16 (frag-linear)
    ushort_t* wcats = wTs + 73728;             //    18,432 bf16 (frag-linear)
    ushort_t* xnb   = wcats + 18432;           // 8,388,608 bf16 (NHWC x)
    ushort_t* prebn = xnb + 8388608;           // 16,777,216 bf16 (NHWC pre-BN)
    float* out      = (float*)d_out;

    prep_mega<<<2409, 256, 0, stream>>>(x, offw, offb, maskw, maskb, convw,
                                        wTs, wcats, bias, gstat, xnb);
    fused_conv_deform<<<512, 1024, 0, stream>>>(xnb, wcats, bias, wTs, prebn, gstat);
    bn_apply_t<<<2048, 256, 0, stream>>>(prebn, gstat, out);
}

// Round 9
// 194.672 us; speedup vs baseline: 1.1155x; 1.0205x over previous
//
#include <hip/hip_runtime.h>
#include <hip/hip_bf16.h>

// Problem constants
#define H_ 128
#define W_ 128
#define HW 16384          // H*W
#define CIN 64
#define COUT 128
#define KK9 9
#define BATCH 8
#define NPIX (BATCH * HW) // 131072
#define KDIM 576          // CIN*KK9

typedef short bf16x8 __attribute__((ext_vector_type(8)));
typedef float f32x4  __attribute__((ext_vector_type(4)));
typedef unsigned short ushort_t;

union U4B { uint4 u; bf16x8 v; };

__device__ __forceinline__ float us2f(unsigned short u) {
    unsigned int v = ((unsigned int)u) << 16;
    float f;
    __builtin_memcpy(&f, &v, 4);
    return f;
}
__device__ __forceinline__ float lo_f(unsigned int w) {
    unsigned int v = w << 16;
    float f;
    __builtin_memcpy(&f, &v, 4);
    return f;
}
__device__ __forceinline__ float hi_f(unsigned int w) {
    unsigned int v = w & 0xffff0000u;
    float f;
    __builtin_memcpy(&f, &v, 4);
    return f;
}
__device__ __forceinline__ unsigned short f2us_bf(float f) {
    __hip_bfloat16 h = __float2bfloat16(f);
    unsigned short u;
    __builtin_memcpy(&u, &h, 2);
    return u;
}
// HW packed f32->bf16 (RNE), 1 inst instead of ~12 for 2 conversions + pack.
__device__ __forceinline__ unsigned int cvtpk_bf16(float a, float b) {
    unsigned int r;
    asm("v_cvt_pk_bf16_f32 %0, %1, %2" : "=v"(r) : "v"(a), "v"(b));
    return r;   // lo16 = bf16(a), hi16 = bf16(b)
}

template <bool F32>
__device__ __forceinline__ float ld_in(const void* p, long i) {
    if (F32) return ((const float*)p)[i];
    return us2f(((const unsigned short*)p)[i]);
}

// ---------------------------------------------------------------------------
// prep bodies (unchanged math).
// ---------------------------------------------------------------------------
template <bool F32>
__device__ __forceinline__ void prep_body(const void* offw, const void* offb,
                                          const void* maskw, const void* maskb,
                                          const void* convw,
                                          ushort_t* wTs, ushort_t* wcats,
                                          float* bias, int i) {
    if (i < 73728) {
        int j = i & 7, lane = (i >> 3) & 63, n = (i >> 9) & 7, ks = i >> 12;
        int co = n * 16 + (lane & 15);
        int k  = ks * 32 + ((lane >> 4) << 3) + j;
        int kk = k >> 6, ci = k & 63;
        wTs[i] = f2us_bf(ld_in<F32>(convw, (long)co * KDIM + ci * 9 + kk));
    } else if (i < 73728 + 18432) {
        int i2 = i - 73728;
        int j = i2 & 7, lane = (i2 >> 3) & 63, n = (i2 >> 9) & 1, ks = i2 >> 10;
        int co2 = n * 16 + (lane & 15);
        int k   = ks * 32 + ((lane >> 4) << 3) + j;
        int kk = k >> 6, ci = k & 63;
        float v = 0.0f;
        if (co2 < 18)      v = ld_in<F32>(offw,  (long)co2 * KDIM + ci * 9 + kk);
        else if (co2 < 27) v = ld_in<F32>(maskw, (long)(co2 - 18) * KDIM + ci * 9 + kk);
        wcats[i2] = f2us_bf(v);
    } else if (i < 73728 + 18432 + 32) {
        int j = i - 73728 - 18432;
        float v = 0.0f;
        if (j < 18)      v = ld_in<F32>(offb, j);
        else if (j < 27) v = ld_in<F32>(maskb, j - 18);
        bias[j] = v;
    }
}

template <bool F32>
__device__ __forceinline__ void transpose_body(const void* x, ushort_t* xnb,
                                               int blk) {
    __shared__ float tile[CIN * 65];
    int b    = blk >> 8;
    int pix0 = (blk & 255) * 64;
    int t    = threadIdx.x;
#pragma unroll
    for (int pass = 0; pass < 4; ++pass) {
        int slot = pass * 256 + t;
        int ci = slot >> 4;          // 0..63
        int f4 = slot & 15;          // 0..15 (4-px chunk)
        long base = (long)(b * CIN + ci) * HW + pix0 + f4 * 4;
        float v0, v1, v2, v3;
        if (F32) {
            float4 v = *(const float4*)((const float*)x + base);
            v0 = v.x; v1 = v.y; v2 = v.z; v3 = v.w;
        } else {
            ushort4 u = *(const ushort4*)((const ushort_t*)x + base);
            v0 = us2f(u.x); v1 = us2f(u.y); v2 = us2f(u.z); v3 = us2f(u.w);
        }
        tile[ci * 65 + f4 * 4 + 0] = v0;
        tile[ci * 65 + f4 * 4 + 1] = v1;
        tile[ci * 65 + f4 * 4 + 2] = v2;
        tile[ci * 65 + f4 * 4 + 3] = v3;
    }
    __syncthreads();
#pragma unroll
    for (int pass = 0; pass < 4; ++pass) {
        int slot = pass * 256 + t;
        int px = slot >> 4;          // 0..63
        int c4 = slot & 15;          // 0..15 (4-ch chunk)
        uint2 o;
        o.x = cvtpk_bf16(tile[(c4 * 4 + 0) * 65 + px], tile[(c4 * 4 + 1) * 65 + px]);
        o.y = cvtpk_bf16(tile[(c4 * 4 + 2) * 65 + px], tile[(c4 * 4 + 3) * 65 + px]);
        *(uint2*)(xnb + (size_t)(b * HW + pix0 + px) * CIN + c4 * 4) = o;
    }
}

// ---------------------------------------------------------------------------
// prep_mega: dtype-probe + prep_weights (blocks 0..360) + transpose_x
// (blocks 361..2408) + gstat zeroing (blocks 0..15).
// ---------------------------------------------------------------------------
__global__ __launch_bounds__(256) void prep_mega(
        const void* __restrict__ x,
        const void* __restrict__ offw,
        const void* __restrict__ offb,
        const void* __restrict__ maskw,
        const void* __restrict__ maskb,
        const void* __restrict__ convw,
        ushort_t* __restrict__ wTs,
        ushort_t* __restrict__ wcats,
        float* __restrict__ bias,
        float* __restrict__ gstat,
        ushort_t* __restrict__ xnb) {
    __shared__ float flagS;
    int t   = threadIdx.x;
    int blk = blockIdx.x;

    if (t < 64) {
        uint4 v = ((const uint4*)x)[t];
        unsigned int w[4] = {v.x, v.y, v.z, v.w};
        int big = 0;
#pragma unroll
        for (int q = 0; q < 4; ++q) {
            big += (((w[q] >> 7)  & 0xFF) >= 0xC0);
            big += (((w[q] >> 23) & 0xFF) >= 0xC0);
        }
        unsigned long long m = __ballot(big > 0);
        if (t == 0) flagS = m ? 1.0f : 0.0f;
    }
    if (blk < 16) gstat[blk * 256 + t] = 0.0f;
    __syncthreads();
    bool isF32 = (flagS != 0.0f);

    if (blk < 361) {
        int i = blk * 256 + t;
        if (isF32) prep_body<true >(offw, offb, maskw, maskb, convw, wTs, wcats, bias, i);
        else       prep_body<false>(offw, offb, maskw, maskb, convw, wTs, wcats, bias, i);
    } else {
        int tb = blk - 361;
        if (isF32) transpose_body<true >(x, xnb, tb);
        else       transpose_body<false>(x, xnb, tb);
    }
}

// ---------------------------------------------------------------------------
// deform helpers.
// ---------------------------------------------------------------------------
__device__ __forceinline__ void compute_tap(int yp_t, int xp_t,
                                            float oy, float ox, float mk,
                                            int* ofs, float* wg) {
    float py  = (float)yp_t + oy;
    float pxf = (float)xp_t + ox;
    float y0f = floorf(py), x0f = floorf(pxf);
    int yi = (int)y0f, xi = (int)x0f;
    float wy1 = py - y0f, wx1 = pxf - x0f;
    float wy0 = 1.0f - wy1, wx0 = 1.0f - wx1;
    int ya  = min(max(yi, 0), H_ - 1);
    int yb  = min(max(yi + 1, 0), H_ - 1);
    int xa  = min(max(xi, 0), W_ - 1);
    int xb2 = min(max(xi + 1, 0), W_ - 1);
    bool vy0 = (yi >= 0) & (yi < H_);
    bool vy1 = (yi >= -1) & (yi < H_ - 1);
    bool vx0 = (xi >= 0) & (xi < W_);
    bool vx1 = (xi >= -1) & (xi < W_ - 1);
    float m0 = mk * wy0, m1 = mk * wy1;
    wg[0] = (vy0 & vx0) ? m0 * wx0 : 0.0f;
    wg[1] = (vy0 & vx1) ? m0 * wx1 : 0.0f;
    wg[2] = (vy1 & vx0) ? m1 * wx0 : 0.0f;
    wg[3] = (vy1 & vx1) ? m1 * wx1 : 0.0f;
    int ra = ya << 13, rb = yb << 13;   // y * W_ * CIN
    int ca = xa << 6,  cb_ = xb2 << 6;  // x * CIN
    ofs[0] = ra + ca;  ofs[1] = ra + cb_;
    ofs[2] = rb + ca;  ofs[3] = rb + cb_;
}

__device__ __forceinline__ void issue_half(const ushort_t* __restrict__ xb,
                                           const int* ofs, int hoff, uint4* cb) {
#pragma unroll
    for (int c = 0; c < 4; ++c)
        cb[c] = *(const uint4*)(xb + ofs[c] + hoff);
}

// consume: interp (f32) + HW cvt_pk pack + 8 MFMAs. No setprio (hurts
// lockstep co-wave issue, m190); pack via v_cvt_pk_bf16_f32 (1 inst vs ~12).
__device__ __forceinline__ void consume_half(int slot, const uint4* cb,
                                             const float* wg,
                                             const ushort_t* __restrict__ ldsB,
                                             int lane, f32x4* acc) {
    float2 v2[4];
#pragma unroll
    for (int j = 0; j < 4; ++j) v2[j] = make_float2(0.f, 0.f);
#pragma unroll
    for (int c = 0; c < 4; ++c) {
        float w = wg[c];
        unsigned int ww[4] = {cb[c].x, cb[c].y, cb[c].z, cb[c].w};
#pragma unroll
        for (int j = 0; j < 4; ++j) {
            v2[j].x = fmaf(w, lo_f(ww[j]), v2[j].x);
            v2[j].y = fmaf(w, hi_f(ww[j]), v2[j].y);
        }
    }
    U4B a;
    a.u = make_uint4(cvtpk_bf16(v2[0].x, v2[0].y), cvtpk_bf16(v2[1].x, v2[1].y),
                     cvtpk_bf16(v2[2].x, v2[2].y), cvtpk_bf16(v2[3].x, v2[3].y));
    const ushort_t* bbase = ldsB + ((size_t)(slot * 8) * 64 + lane) * 8;
#pragma unroll
    for (int n = 0; n < 8; ++n) {
        bf16x8 bf = *(const bf16x8*)(bbase + n * 64 * 8);
        acc[n] = __builtin_amdgcn_mfma_f32_16x16x32_bf16(a.v, bf, acc[n], 0, 0, 0);
    }
}

// sched_barrier mask: pin ONLY VMEM (gathers can't sink below their slot —
// R0's failure mode); ALU/VALU/SALU/MFMA/DS may cross so each wave's issue-
// VALU can fill its consume stalls (breaks the 4-wave convoy that made the
// pipes run serially: VALU 28us + L1 15us + LDS 15us + MFMA 8us ~ sum not max).
#define SB_PIN_VMEM() __builtin_amdgcn_sched_barrier(0x38F)

// ---------------------------------------------------------------------------
// fused_conv_deform: conv phase (x-tile in LDS, swizzled) + deform phase
// (B K-split 2x, half-tap LA-2 ring). R8 structure, R9 schedule.
// ---------------------------------------------------------------------------
__global__ __launch_bounds__(1024, 4) void fused_conv_deform(
        const ushort_t* __restrict__ xnb,
        const ushort_t* __restrict__ wcats,
        const float* __restrict__ bias,
        const ushort_t* __restrict__ wTs,
        ushort_t* __restrict__ prebn,
        float* __restrict__ gstat) {
    __shared__ uint4 lds[8192];   // 131,072 B

    float2* offL  = (float2*)(lds + 6400);   // 9*256 float2 (18,432 B)
    float*  maskS = (float*) (lds + 7552);   // 9*256 f32    ( 9,216 B)
    float*  red   = (float*) (lds + 8128);   // 256 f32      ( 1,024 B)

    int t    = threadIdx.x;
    int bid  = blockIdx.x;
    int sbid = (bid & 7) * 64 + (bid >> 3);   // 512 = 8 XCDs x 64, bijective
    int pix0 = sbid * 256;
    int b    = pix0 >> 14;
    int rem0 = pix0 & 16383;
    int y0   = rem0 >> 7;

    // ---- phase 0: stage convB + 4-row x-tile (swizzled) ----
    const uint4* wc4 = (const uint4*)wcats;
    for (int i = t; i < 2304; i += 1024) lds[i] = wc4[i];
    const uint4* xrow4 = (const uint4*)(xnb + (size_t)b * HW * CIN);
    int sxq = t >> 3, sc16 = t & 7;
#pragma unroll
    for (int r = 0; r < 4; ++r) {
        int gy = y0 - 1 + r;
        if (gy >= 0 && gy < H_) {
            uint4 v = xrow4[(size_t)gy * 1024 + t];
            lds[2304 + r * 1024 + sxq * 8 + (sc16 ^ (sxq & 7))] = v;
        }
    }
    if (t < 256) red[t] = 0.0f;
    __syncthreads();

    int wave = t >> 6, lane = t & 63, mrow = lane & 15, quad = lane >> 4;
    int px_l = wave * 16 + mrow;

    // ---- phase 1: conv 27-ch -> offL/maskS in LDS ----
    {
        int ly = px_l >> 7;
        int xp = px_l & 127;
        uint4 af0[9], af1[9];
#pragma unroll
        for (int kk = 0; kk < 9; ++kk) {
            int ty = kk / 3, tx = kk % 3;
            int tr = ly + ty;
            int gy = y0 - 1 + tr;
            int xq = xp + tx - 1;
            bool ok = (gy >= 0) && (gy < H_) && (xq >= 0) && (xq < W_);
            int xc = min(max(xq, 0), W_ - 1);
            int base = 2304 + tr * 1024 + xc * 8;
            uint4 a0 = lds[base + ((quad    ) ^ (xc & 7))];
            uint4 a1 = lds[base + ((quad + 4) ^ (xc & 7))];
            af0[kk] = ok ? a0 : make_uint4(0, 0, 0, 0);
            af1[kk] = ok ? a1 : make_uint4(0, 0, 0, 0);
        }
        f32x4 cacc[2];
        cacc[0] = (f32x4){0.f, 0.f, 0.f, 0.f};
        cacc[1] = (f32x4){0.f, 0.f, 0.f, 0.f};
        const ushort_t* ldsBc = (const ushort_t*)lds;
#pragma unroll
        for (int kk = 0; kk < 9; ++kk) {
#pragma unroll
            for (int half = 0; half < 2; ++half) {
                int ks = kk * 2 + half;
                U4B a; a.u = half ? af1[kk] : af0[kk];
#pragma unroll
                for (int n = 0; n < 2; ++n) {
                    bf16x8 bf = *(const bf16x8*)(ldsBc + ((ks * 2 + n) * 64 + lane) * 8);
                    cacc[n] = __builtin_amdgcn_mfma_f32_16x16x32_bf16(a.v, bf, cacc[n], 0, 0, 0);
                }
            }
        }
#pragma unroll
        for (int n = 0; n < 2; ++n) {
            int co2 = n * 16 + mrow;
            if (co2 >= 27) continue;
            float bs = bias[co2];
#pragma unroll
            for (int r = 0; r < 4; ++r) {
                int px = wave * 16 + quad * 4 + r;
                float v = cacc[n][r] + bs;
                if (co2 < 18)
                    ((float*)offL)[((co2 >> 1) * 256 + px) * 2 + (co2 & 1)] = v;
                else
                    maskS[(co2 - 18) * 256 + px] = 1.0f / (1.0f + __expf(-v));
            }
        }
    }
    __syncthreads();   // x-tile/convB reads done; offL/maskS visible

    // ---- phase 2: stage deform B half0 + gather-ring prologue ----
    const uint4* ws4 = (const uint4*)wTs;
    for (int i = t; i < 4608; i += 1024) lds[i] = ws4[i];

    int remp = rem0 + px_l;
    int yp  = remp >> 7, xp2 = remp & 127;
    const ushort_t* xb = xnb + (size_t)b * HW * CIN + quad * 8;

    f32x4 acc[8];
#pragma unroll
    for (int n = 0; n < 8; ++n) acc[n] = (f32x4){0.f, 0.f, 0.f, 0.f};

    int   ofs[2][4];
    float wg[2][4];
    uint4 cb[3][4];

    float2 oE  = offL[px_l];           float mkE = maskS[px_l];
    float2 oO  = offL[256 + px_l];     float mkO = maskS[256 + px_l];
    compute_tap(yp - 1, xp2 - 1, oE.x, oE.y, mkE, ofs[0], wg[0]);
    issue_half(xb, ofs[0], 0,  cb[0]);
    issue_half(xb, ofs[0], 32, cb[1]);
    oE = offL[2 * 256 + px_l];  mkE = maskS[2 * 256 + px_l];
    SB_PIN_VMEM();
    __syncthreads();   // B half0 visible

    const ushort_t* ldsB = (const ushort_t*)lds;

#pragma unroll
    for (int hs = 0; hs < 9; ++hs) {
        const int hs2 = hs + 2;                // 2..10, always valid
        {
            const int kk2 = hs2 >> 1;
            const int s2  = hs2 % 3;
            if ((hs2 & 1) == 0) {
                const int tp2 = kk2 & 1;
                float ooy = tp2 ? oO.x : oE.x;
                float oox = tp2 ? oO.y : oE.y;
                float omk = tp2 ? mkO  : mkE;
                compute_tap(yp + kk2 / 3 - 1, xp2 + kk2 % 3 - 1, ooy, oox, omk,
                            ofs[tp2], wg[tp2]);
                issue_half(xb, ofs[tp2], 0, cb[s2]);
                if (kk2 + 2 <= 8) {
                    float2 o = offL[(kk2 + 2) * 256 + px_l];
                    float  m = maskS[(kk2 + 2) * 256 + px_l];
                    if (tp2) { oO = o; mkO = m; } else { oE = o; mkE = m; }
                }
            } else {
                issue_half(xb, ofs[kk2 & 1], 32, cb[s2]);
            }
        }
        SB_PIN_VMEM();
        consume_half(hs, cb[hs % 3], wg[(hs >> 1) & 1], ldsB, lane, acc);
    }
    __syncthreads();   // half0 reads done
    for (int i = t; i < 4608; i += 1024) lds[i] = ws4[4608 + i];
    __syncthreads();   // half1 visible

#pragma unroll
    for (int hs = 9; hs < 18; ++hs) {
        const int hs2 = hs + 2;
        if (hs2 < 18) {
            const int kk2 = hs2 >> 1;
            const int s2  = hs2 % 3;
            if ((hs2 & 1) == 0) {
                const int tp2 = kk2 & 1;
                float ooy = tp2 ? oO.x : oE.x;
                float oox = tp2 ? oO.y : oE.y;
                float omk = tp2 ? mkO  : mkE;
                compute_tap(yp + kk2 / 3 - 1, xp2 + kk2 % 3 - 1, ooy, oox, omk,
                            ofs[tp2], wg[tp2]);
                issue_half(xb, ofs[tp2], 0, cb[s2]);
                if (kk2 + 2 <= 8) {
                    float2 o = offL[(kk2 + 2) * 256 + px_l];
                    float  m = maskS[(kk2 + 2) * 256 + px_l];
                    if (tp2) { oO = o; mkO = m; } else { oE = o; mkE = m; }
                }
            } else {
                issue_half(xb, ofs[kk2 & 1], 32, cb[s2]);
            }
        }
        SB_PIN_VMEM();
        consume_half(hs - 9, cb[hs % 3], wg[(hs >> 1) & 1], ldsB, lane, acc);
    }

    // ---- epilogue: bf16 NHWC store + BN stats (shuffle-reduce) ----
#pragma unroll
    for (int n = 0; n < 8; ++n) {
        int co = n * 16 + mrow;
        float s = 0.f, ss = 0.f;
#pragma unroll
        for (int r = 0; r < 4; ++r) {
            int pg = pix0 + wave * 16 + quad * 4 + r;
            float v = acc[n][r];
            prebn[(size_t)pg * COUT + co] = f2us_bf(v);
            s += v;
            ss += v * v;
        }
        s  += __shfl_xor(s, 16, 64);
        s  += __shfl_xor(s, 32, 64);
        ss += __shfl_xor(ss, 16, 64);
        ss += __shfl_xor(ss, 32, 64);
        if (quad == 0) {
            atomicAdd(&red[co], s);
            atomicAdd(&red[128 + co], ss);
        }
    }
    __syncthreads();
    if (t < 256) atomicAdd(&gstat[(bid & 15) * 256 + t], red[t]);
}

// ---------------------------------------------------------------------------
// bn_apply_t: derive mean/rstd from gstat; vectorized uint4 reads + float4
// writes via padded LDS transpose tile.
// ---------------------------------------------------------------------------
__global__ __launch_bounds__(256) void bn_apply_t(const ushort_t* __restrict__ prebn,
                                                  const float* __restrict__ gstat,
                                                  float* __restrict__ out) {
    __shared__ float tile[128 * 65];
    __shared__ float mvs[256];
    int t = threadIdx.x;
    if (t < 128) {
        float s = 0.f, ss = 0.f;
#pragma unroll
        for (int part = 0; part < 16; ++part) {
            s  += gstat[part * 256 + t];
            ss += gstat[part * 256 + 128 + t];
        }
        const float invN = 1.0f / (float)NPIX;
        float mean = s * invN;
        float var  = ss * invN - mean * mean;
        if (!isfinite(mean)) mean = 0.0f;
        float r = rsqrtf(fmaxf(var, 0.0f) + 1e-5f);
        if (!isfinite(r)) r = 1.0f;
        mvs[t]       = mean;
        mvs[128 + t] = r;
    }
    __syncthreads();
    int pix0 = blockIdx.x * 64;
    int b    = pix0 >> 14;
    int rem0 = pix0 & 16383;
    const uint4* src4 = (const uint4*)(prebn + (size_t)pix0 * COUT);
#pragma unroll
    for (int r = 0; r < 4; ++r) {
        int i  = r * 256 + t;        // uint4 index 0..1023
        uint4 v = src4[i];
        int p  = i >> 4;             // pixel 0..63
        int c0 = (i & 15) * 8;       // channel base
        unsigned int w[4] = {v.x, v.y, v.z, v.w};
#pragma unroll
        for (int j = 0; j < 4; ++j) {
            int c = c0 + j * 2;
            float f0 = lo_f(w[j]);
            float f1 = hi_f(w[j]);
            tile[c * 65 + p]       = fmaxf((f0 - mvs[c])     * mvs[128 + c],     0.0f);
            tile[(c + 1) * 65 + p] = fmaxf((f1 - mvs[c + 1]) * mvs[128 + c + 1], 0.0f);
        }
    }
    __syncthreads();
#pragma unroll
    for (int r = 0; r < 8; ++r) {
        int i  = r * 256 + t;        // float4 index 0..2047
        int c2 = i >> 4;             // 0..127
        int q  = (i & 15) * 4;       // 0..60
        float4 w4 = make_float4(tile[c2 * 65 + q],     tile[c2 * 65 + q + 1],
                                tile[c2 * 65 + q + 2], tile[c2 * 65 + q + 3]);
        *(float4*)(out + (size_t)(b * COUT + c2) * HW + rem0 + q) = w4;
    }
}

// ---------------------------------------------------------------------------
extern "C" void kernel_launch(void* const* d_in, const int* in_sizes, int n_in,
                              void* d_out, int out_size, void* d_ws, size_t ws_size,
                              hipStream_t stream) {
    (void)in_sizes; (void)n_in; (void)out_size; (void)ws_size;
    const void* x     = d_in[0];
    const void* offw  = d_in[1];
    const void* offb  = d_in[2];
    const void* maskw = d_in[3];
    const void* maskb = d_in[4];
    const void* convw = d_in[5];

    float* ws       = (float*)d_ws;
    float* off2     = ws;                      // (unused after fusion)
    float* mask_ws  = off2 + 2359296;          // (unused after fusion)
    float* bias     = mask_ws + 1179648;       //        32 f32
    float* gstat    = bias + 32;               //     4,096 f32
    float* flag     = gstat + 4096;            //        16 f32 (unused now)
    ushort_t* wTs   = (ushort_t*)(flag + 16);  //    73,728 bf16 (frag-linear)
    ushort_t* wcats = wTs + 73728;             //    18,432 bf16 (frag-linear)
    ushort_t* xnb   = wcats + 18432;           // 8,388,608 bf16 (NHWC x)
    ushort_t* prebn = xnb + 8388608;           // 16,777,216 bf16 (NHWC pre-BN)
    float* out      = (float*)d_out;

    prep_mega<<<2409, 256, 0, stream>>>(x, offw, offb, maskw, maskb, convw,
                                        wTs, wcats, bias, gstat, xnb);
    fused_conv_deform<<<512, 1024, 0, stream>>>(xnb, wcats, bias, wTs, prebn, gstat);
    bn_apply_t<<<2048, 256, 0, stream>>>(prebn, gstat, out);
}